// Round 2
// baseline (1247.725 us; speedup 1.0000x reference)
//
#include <hip/hip_runtime.h>

typedef unsigned short u16;
typedef unsigned int   u32;
typedef __attribute__((ext_vector_type(4))) float f32x4;
typedef __attribute__((ext_vector_type(8))) u16   u16x8;
typedef __attribute__((ext_vector_type(4))) u16   u16x4;

// ---------------- helpers ----------------
__device__ __forceinline__ u16 f2bf(float x) {
  u32 u = __builtin_bit_cast(u32, x);
  u = (u + 0x7fffu + ((u >> 16) & 1u)) >> 16;
  return (u16)u;
}
__device__ __forceinline__ float bf2f(u16 h) {
  return __builtin_bit_cast(float, (u32)h << 16);
}
__device__ __forceinline__ float fast_sig(float x) { return 1.f / (1.f + __expf(-x)); }
__device__ __forceinline__ float fast_tanh(float x) {
  float e = __expf(2.f * x);
  return 1.f - 2.f / (e + 1.f);
}

__device__ __forceinline__ f32x4 mfma_bf16(u16x8 a, u16x8 b, f32x4 c) {
  asm volatile("v_mfma_f32_16x16x32_bf16 %0, %1, %2, %0" : "+v"(c) : "v"(a), "v"(b));
  return c;
}

__device__ __forceinline__ void gload_lds16(const void* g, void* l) {
  __builtin_amdgcn_global_load_lds(
      (__attribute__((address_space(1))) u32*)g,
      (__attribute__((address_space(3))) u32*)l, 16, 0, 0);
}

// ---------------- prep kernels ----------------
__global__ __launch_bounds__(256) void k_f32_to_bf16(const float* __restrict__ s,
                                                     u16* __restrict__ d, int n) {
  int i = (blockIdx.x * 256 + threadIdx.x) * 4;
  if (i + 4 <= n) {
    f32x4 v = *(const f32x4*)(s + i);
    u16x4 o;
    o.x = f2bf(v.x); o.y = f2bf(v.y); o.z = f2bf(v.z); o.w = f2bf(v.w);
    *(u16x4*)(d + i) = o;
  } else {
    for (; i < n; ++i) d[i] = f2bf(s[i]);
  }
}

// W_cat = [W_ih | W_hh] rows of length 1280, bf16
__global__ __launch_bounds__(256) void k_build_wcat(const float* __restrict__ Wih,
                                                    const float* __restrict__ Whh,
                                                    u16* __restrict__ d) {
  int i = blockIdx.x * 256 + threadIdx.x;  // [0, 2048*1280)
  int r = i / 1280, c = i - r * 1280;
  float v = (c < 768) ? Wih[r * 768 + c] : Whh[r * 512 + (c - 768)];
  d[i] = f2bf(v);
}

// W_gen padded to 6656 rows (rows >= 6624 zero)
__global__ __launch_bounds__(256) void k_build_wgen(const float* __restrict__ Wg,
                                                    u16* __restrict__ d) {
  int i = blockIdx.x * 256 + threadIdx.x;  // [0, 6656*512)
  int r = i >> 9;
  d[i] = f2bf(r < 6624 ? Wg[i] : 0.f);
}

__global__ __launch_bounds__(256) void k_bias_cat(const float* __restrict__ a,
                                                  const float* __restrict__ b,
                                                  float* __restrict__ d) {
  int i = blockIdx.x * 256 + threadIdx.x;  // 2048
  d[i] = a[i] + b[i];
}

// WT[k][j] = W_h2h[j][k], 512x512, bf16 (k-major for coalesced GEMV in step_attn)
__global__ __launch_bounds__(256) void k_transpose_w(const float* __restrict__ in,
                                                     u16* __restrict__ out) {
  __shared__ u16 t[32][33];
  const int bx = blockIdx.x * 32;  // k-tile (out rows)
  const int by = blockIdx.y * 32;  // j-tile (out cols)
  const int tx = threadIdx.x & 31, ty4 = (threadIdx.x >> 5) * 4;
#pragma unroll
  for (int i = 0; i < 4; ++i)
    t[ty4 + i][tx] = f2bf(in[(size_t)(by + ty4 + i) * 512 + bx + tx]);
  __syncthreads();
#pragma unroll
  for (int i = 0; i < 4; ++i)
    out[(size_t)(bx + ty4 + i) * 512 + by + tx] = t[tx][ty4 + i];
}

// ---------------- GEMM: C[M,N] = A[M,K] * B[N,K]^T (+bias), bf16 in, f32 acc ----------------
// OUT_MODE: 1 = f32 + bias, 2 = bf16 (no bias)
template <int BM, int BN, int WM, int WN, int OUT_MODE>
__global__ __launch_bounds__(256) void gemm_bt(const u16* __restrict__ A, int lda,
                                               const u16* __restrict__ B, int ldb,
                                               const float* __restrict__ bias,
                                               float* __restrict__ Cf, u16* __restrict__ Cb,
                                               int ldc, int Nreal, int K) {
  static_assert((BM / WM) * (BN / WN) == 4, "4 waves");
  constexpr int FM = WM / 16, FN = WN / 16;
  constexpr int NWC = BN / WN;
  constexpr int CHA = (BM * 4) / 256, CHB = (BN * 4) / 256;
  __shared__ __align__(16) u16 sA[BM * 32];
  __shared__ __align__(16) u16 sB[BN * 32];
  const int tid = threadIdx.x;
  const int lane = tid & 63, wave = tid >> 6;
  const int wr = wave / NWC, wc = wave % NWC;
  const int l15 = lane & 15, lhi = lane >> 4;
  const int m0 = blockIdx.y * BM, n0 = blockIdx.x * BN;

  f32x4 acc[FM][FN];
#pragma unroll
  for (int i = 0; i < FM; ++i)
#pragma unroll
    for (int j = 0; j < FN; ++j) acc[i][j] = 0.f;

  for (int k0 = 0; k0 < K; k0 += 32) {
    __syncthreads();
#pragma unroll
    for (int j = 0; j < CHA; ++j) {
      int idx = j * 256 + tid;
      int row = idx >> 2, cc = idx & 3;
      int c = cc ^ ((row >> 1) & 3);
      gload_lds16(A + (size_t)(m0 + row) * lda + (k0 + c * 8), sA + idx * 8);
    }
#pragma unroll
    for (int j = 0; j < CHB; ++j) {
      int idx = j * 256 + tid;
      int row = idx >> 2, cc = idx & 3;
      int c = cc ^ ((row >> 1) & 3);
      gload_lds16(B + (size_t)(n0 + row) * ldb + (k0 + c * 8), sB + idx * 8);
    }
    __syncthreads();

    u16x8 av[FM], bv[FN];
#pragma unroll
    for (int mi = 0; mi < FM; ++mi) {
      int row = wr * WM + mi * 16 + l15;
      int ch = row * 4 + (lhi ^ ((row >> 1) & 3));
      av[mi] = *(const u16x8*)(sA + ch * 8);
    }
#pragma unroll
    for (int ni = 0; ni < FN; ++ni) {
      int row = wc * WN + ni * 16 + l15;
      int ch = row * 4 + (lhi ^ ((row >> 1) & 3));
      bv[ni] = *(const u16x8*)(sB + ch * 8);
    }
#pragma unroll
    for (int mi = 0; mi < FM; ++mi)
#pragma unroll
      for (int ni = 0; ni < FN; ++ni) acc[mi][ni] = mfma_bf16(av[mi], bv[ni], acc[mi][ni]);
  }

  asm volatile("s_nop 7\ns_nop 7\ns_nop 7");  // MFMA->VALU hazard guard

#pragma unroll
  for (int mi = 0; mi < FM; ++mi) {
#pragma unroll
    for (int ni = 0; ni < FN; ++ni) {
      int col = n0 + wc * WN + ni * 16 + l15;
      if (col < Nreal) {
        float bvv = (OUT_MODE == 1) ? bias[col] : 0.f;
#pragma unroll
        for (int r = 0; r < 4; ++r) {
          int row = m0 + wr * WM + mi * 16 + lhi * 4 + r;
          float v = acc[mi][ni][r] + bvv;
          if (OUT_MODE == 2)
            Cb[(size_t)row * ldc + col] = f2bf(v);
          else
            Cf[(size_t)row * ldc + col] = v;
        }
      }
    }
  }
}

// ---------------- fused per-step attention (hp GEMV + score + softmax + ctx + ce) ----------------
// block b (256 blocks, 256 thr):
//  hp[j] = b_h2h[j] + sum_k h[k] * W_h2h[j][k]  (WT k-major, 4 k-groups x 64 col-groups)
//  e[t]  = sum_h tanh(Hproj[b,t,h] + hp[h]) * w_score[h]; alpha = softmax_t(e)
//  ctx[d]= sum_t alpha[t] * batch_H[b,t,d]; writes ctx|ce into Acat
__global__ __launch_bounds__(256) void step_attn(const u16* __restrict__ Hproj,
                                                 const u16* __restrict__ WT,
                                                 const float* __restrict__ b_h2h,
                                                 const float* __restrict__ wsc,
                                                 const u16* __restrict__ bh,
                                                 const u16* __restrict__ embb,
                                                 const int* __restrict__ text, int step,
                                                 u16* __restrict__ Acat) {
  const int b = blockIdx.x, tid = threadIdx.x;
  __shared__ float hsm[512];
  __shared__ float part[4][512];
  __shared__ float hpsp[528];  // padded: idx j -> j + (j>>5), kills 16-way stride-32 conflict
  __shared__ float wssp[528];
  __shared__ float es[64];

  {  // load h (prev step) and w_score
    u32 w2 = *(const u32*)(Acat + b * 1280 + 768 + tid * 2);
    hsm[tid * 2] = bf2f((u16)(w2 & 0xffffu));
    hsm[tid * 2 + 1] = bf2f((u16)(w2 >> 16));
    int j0 = tid * 2;
    int pi = j0 + (j0 >> 5);
    wssp[pi] = wsc[j0];
    wssp[pi + 1] = wsc[j0 + 1];
  }
  __syncthreads();

  {  // hp partials: kg in [0,4), cols cg*8..cg*8+7
    const int kg = tid >> 6, cg = tid & 63;
    float acc[8] = {0.f, 0.f, 0.f, 0.f, 0.f, 0.f, 0.f, 0.f};
    const u16* wrow = WT + (size_t)(kg * 128) * 512 + cg * 8;
#pragma unroll 4
    for (int kk = 0; kk < 128; ++kk) {
      float hk = hsm[kg * 128 + kk];
      u16x8 wv = *(const u16x8*)(wrow + (size_t)kk * 512);
#pragma unroll
      for (int j = 0; j < 8; ++j) acc[j] = fmaf(hk, bf2f(wv[j]), acc[j]);
    }
#pragma unroll
    for (int j = 0; j < 8; ++j) part[kg][cg * 8 + j] = acc[j];
  }
  __syncthreads();
  {  // reduce k-groups + bias -> padded hp
    int j0 = tid * 2;
#pragma unroll
    for (int q = 0; q < 2; ++q) {
      int j = j0 + q;
      float v = part[0][j] + part[1][j] + part[2][j] + part[3][j] + b_h2h[j];
      hpsp[j + (j >> 5)] = v;
    }
  }
  __syncthreads();

  // scores: thread group (tid&15) owns 32-wide h-chunk; hp/w chunk cached in regs
  const int ch16 = tid & 15;
  const int hbase = ch16 * 33;
  const int hc = ch16 * 32;
  float hpr[32], wsr[32];
#pragma unroll
  for (int j = 0; j < 32; ++j) {
    hpr[j] = hpsp[hbase + j];
    wsr[j] = wssp[hbase + j];
  }
#pragma unroll
  for (int tg = 0; tg < 4; ++tg) {
    int t = tg * 16 + (tid >> 4);
    const u16* hr = Hproj + (size_t)(b * 64 + t) * 512 + hc;
    float s = 0.f;
#pragma unroll
    for (int jo = 0; jo < 32; jo += 8) {
      u16x8 hv = *(const u16x8*)(hr + jo);
#pragma unroll
      for (int j = 0; j < 8; ++j) {
        float x = bf2f(hv[j]) + hpr[jo + j];
        s += fast_tanh(x) * wsr[jo + j];
      }
    }
#pragma unroll
    for (int off = 8; off; off >>= 1) s += __shfl_xor(s, off, 16);
    if (ch16 == 0) es[t] = s;
  }
  __syncthreads();
  if (tid < 64) {  // softmax over t
    float v = es[tid];
    float m = v;
#pragma unroll
    for (int o = 32; o; o >>= 1) m = fmaxf(m, __shfl_xor(m, o, 64));
    float p = __expf(v - m);
    float su = p;
#pragma unroll
    for (int o = 32; o; o >>= 1) su += __shfl_xor(su, o, 64);
    es[tid] = p / su;
  }
  __syncthreads();
  // context + ce gather
  const u16* base = bh + (size_t)b * 32768 + tid * 2;
  float c0 = 0.f, c1 = 0.f;
#pragma unroll 8
  for (int t = 0; t < 64; ++t) {
    u32 w = *(const u32*)(base + t * 512);
    float a = es[t];
    c0 = fmaf(a, bf2f((u16)(w & 0xffffu)), c0);
    c1 = fmaf(a, bf2f((u16)(w >> 16)), c1);
  }
  u32 pk = (u32)f2bf(c0) | ((u32)f2bf(c1) << 16);
  *(u32*)(Acat + b * 1280 + tid * 2) = pk;
  int ci = text[b * 26 + step];
  Acat[b * 1280 + 512 + tid] = embb[(size_t)ci * 256 + tid];
}

// ---------------- fused gates GEMM + LSTM cell ----------------
// grid (16, 4): jt = 32-wide j-tile, b0 = 64-wide batch tile. Block computes the
// 4 gate segments (i,f,g,o) for its (64 b x 32 j) tile as a BM=64 x BN=128 MFMA GEMM
// (B rows gathered from seg*512 + jt*32 + jl), exchanges gates via LDS, applies the
// LSTM cell, writes h (bf16) to Acat + hsb and c (f32) to cst.
__global__ __launch_bounds__(256) void step_gates(const u16* __restrict__ A,
                                                  const u16* __restrict__ Wc,
                                                  const float* __restrict__ biascat,
                                                  float* __restrict__ cst,
                                                  u16* __restrict__ Acat,
                                                  u16* __restrict__ hsb, int step) {
  __shared__ __align__(16) u16 sA[64 * 32];
  __shared__ __align__(16) u16 sB[128 * 32];
  __shared__ float gsm[64][132];
  const int tid = threadIdx.x;
  const int lane = tid & 63, wave = tid >> 6;
  const int wr = wave >> 1, wc = wave & 1;  // WM=32, WN=64
  const int l15 = lane & 15, lhi = lane >> 4;
  const int jt = blockIdx.x;       // 0..15
  const int b0 = blockIdx.y * 64;  // 0..3

  f32x4 acc[2][4];
#pragma unroll
  for (int i = 0; i < 2; ++i)
#pragma unroll
    for (int j = 0; j < 4; ++j) acc[i][j] = 0.f;

  for (int k0 = 0; k0 < 1280; k0 += 32) {
    __syncthreads();
    {  // stage A: 64 rows (CHA=1)
      int row = tid >> 2, cc = tid & 3;
      int c = cc ^ ((row >> 1) & 3);
      gload_lds16(A + (size_t)(b0 + row) * 1280 + (k0 + c * 8), sA + tid * 8);
    }
#pragma unroll
    for (int j = 0; j < 2; ++j) {  // stage B: 128 rows from 4 gate segments
      int idx = j * 256 + tid;
      int row = idx >> 2, cc = idx & 3;
      int c = cc ^ ((row >> 1) & 3);
      int grow = (row >> 5) * 512 + jt * 32 + (row & 31);
      gload_lds16(Wc + (size_t)grow * 1280 + (k0 + c * 8), sB + idx * 8);
    }
    __syncthreads();

    u16x8 av[2], bv[4];
#pragma unroll
    for (int mi = 0; mi < 2; ++mi) {
      int row = wr * 32 + mi * 16 + l15;
      int ch = row * 4 + (lhi ^ ((row >> 1) & 3));
      av[mi] = *(const u16x8*)(sA + ch * 8);
    }
#pragma unroll
    for (int ni = 0; ni < 4; ++ni) {
      int row = wc * 64 + ni * 16 + l15;
      int ch = row * 4 + (lhi ^ ((row >> 1) & 3));
      bv[ni] = *(const u16x8*)(sB + ch * 8);
    }
#pragma unroll
    for (int mi = 0; mi < 2; ++mi)
#pragma unroll
      for (int ni = 0; ni < 4; ++ni) acc[mi][ni] = mfma_bf16(av[mi], bv[ni], acc[mi][ni]);
  }

  asm volatile("s_nop 7\ns_nop 7\ns_nop 7");  // MFMA->VALU hazard guard

#pragma unroll
  for (int mi = 0; mi < 2; ++mi)
#pragma unroll
    for (int ni = 0; ni < 4; ++ni) {
      int col = wc * 64 + ni * 16 + l15;
      int row = wr * 32 + mi * 16 + lhi * 4;
#pragma unroll
      for (int r = 0; r < 4; ++r) gsm[row + r][col] = acc[mi][ni][r];
    }
  __syncthreads();

  {  // LSTM cell: thread owns bl = tid>>2, jl = (tid&3)*8 .. +7
    const int bl = tid >> 2, jl0 = (tid & 3) * 8;
    const int b = b0 + bl;
    const int jg0 = jt * 32 + jl0;  // global j base
    float cn[8];
    u16 hb[8];
#pragma unroll
    for (int q = 0; q < 8; ++q) {
      int jl = jl0 + q, j = jg0 + q;
      float iv = fast_sig(gsm[bl][jl] + biascat[j]);
      float fv = fast_sig(gsm[bl][32 + jl] + biascat[512 + j]);
      float gv = fast_tanh(gsm[bl][64 + jl] + biascat[1024 + j]);
      float ov = fast_sig(gsm[bl][96 + jl] + biascat[1536 + j]);
      float c = fv * cst[(size_t)b * 512 + j] + iv * gv;
      cn[q] = c;
      hb[q] = f2bf(ov * fast_tanh(c));
    }
    *(f32x4*)(cst + (size_t)b * 512 + jg0) = *(f32x4*)cn;
    *(f32x4*)(cst + (size_t)b * 512 + jg0 + 4) = *(f32x4*)(cn + 4);
    *(u16x8*)(Acat + (size_t)b * 1280 + 768 + jg0) = *(u16x8*)hb;
    *(u16x8*)(hsb + (size_t)(b * 26 + step) * 512 + jg0) = *(u16x8*)hb;
  }
}

// ---------------- launch ----------------
extern "C" void kernel_launch(void* const* d_in, const int* in_sizes, int n_in,
                              void* d_out, int out_size, void* d_ws, size_t ws_size,
                              hipStream_t stream) {
  const float* batch_H = (const float*)d_in[0];
  const int*   text    = (const int*)d_in[1];
  const float* W_i2h   = (const float*)d_in[2];
  const float* W_h2h   = (const float*)d_in[3];
  const float* b_h2h   = (const float*)d_in[4];
  const float* w_score = (const float*)d_in[5];
  const float* W_ih    = (const float*)d_in[6];
  const float* W_hh    = (const float*)d_in[7];
  const float* b_ih    = (const float*)d_in[8];
  const float* b_hh    = (const float*)d_in[9];
  const float* emb     = (const float*)d_in[10];
  const float* W_gen   = (const float*)d_in[11];
  const float* b_gen   = (const float*)d_in[12];
  float* out = (float*)d_out;

  // Big bf16 scratch at the front of d_out (fully overwritten by the final GEMM,
  // which reads only hsb/Wgenb).
  u16* bHb   = (u16*)d_out;          // 16 MB
  u16* Hproj = bHb + 8388608;        // 16 MB

  char* w = (char*)d_ws;
  auto alloc = [&](size_t bytes) {
    char* p = w;
    w += (bytes + 255) & ~(size_t)255;
    return p;
  };
  u16*   Wi2hb   = (u16*)alloc(512ull * 512 * 2);
  u16*   WTb     = (u16*)alloc(512ull * 512 * 2);   // W_h2h^T, k-major
  u16*   Wcatb   = (u16*)alloc(2048ull * 1280 * 2);
  u16*   Wgenb   = (u16*)alloc(6656ull * 512 * 2);
  u16*   embb    = (u16*)alloc(6624ull * 256 * 2);
  float* biascat = (float*)alloc(2048ull * 4);
  u16*   Acat    = (u16*)alloc(256ull * 1280 * 2);  // [ctx(512) | ce(256) | h(512)]
  float* cst     = (float*)alloc(256ull * 512 * 4);
  u16*   hsb     = (u16*)alloc(6656ull * 512 * 2);

  hipMemsetAsync(Acat, 0, 256ull * 1280 * 2, stream);  // h0 = 0
  hipMemsetAsync(cst, 0, 256ull * 512 * 4, stream);    // c0 = 0

  k_f32_to_bf16<<<8192, 256, 0, stream>>>(batch_H, bHb, 8388608);
  k_f32_to_bf16<<<256, 256, 0, stream>>>(W_i2h, Wi2hb, 262144);
  k_transpose_w<<<dim3(16, 16), 256, 0, stream>>>(W_h2h, WTb);
  k_f32_to_bf16<<<1656, 256, 0, stream>>>(emb, embb, 1695744);
  k_build_wcat<<<10240, 256, 0, stream>>>(W_ih, W_hh, Wcatb);
  k_build_wgen<<<13312, 256, 0, stream>>>(W_gen, Wgenb);
  k_bias_cat<<<8, 256, 0, stream>>>(b_ih, b_hh, biascat);

  // Hproj = batch_H @ W_i2h^T -> bf16
  gemm_bt<128, 128, 64, 64, 2><<<dim3(4, 128), 256, 0, stream>>>(
      bHb, 512, Wi2hb, 512, nullptr, nullptr, Hproj, 512, 512, 512);

  for (int s = 0; s < 26; ++s) {
    step_attn<<<256, 256, 0, stream>>>(Hproj, WTb, b_h2h, w_score, bHb, embb, text, s, Acat);
    step_gates<<<dim3(16, 4), 256, 0, stream>>>(Acat, Wcatb, biascat, cst, Acat, hsb, s);
  }

  // probs = hs @ W_gen^T + b_gen -> f32 out (M=6656, N=6624, K=512)
  gemm_bt<128, 128, 64, 64, 1><<<dim3(52, 52), 256, 0, stream>>>(
      hsb, 512, Wgenb, 512, b_gen, out, nullptr, 6624, 6624, 512);

  (void)in_sizes; (void)n_in; (void)out_size; (void)ws_size;
}

// Round 3
// 1003.545 us; speedup vs baseline: 1.2433x; 1.2433x over previous
//
#include <hip/hip_runtime.h>

typedef unsigned short u16;
typedef unsigned int   u32;
typedef __attribute__((ext_vector_type(4))) float f32x4;
typedef __attribute__((ext_vector_type(8))) u16   u16x8;
typedef __attribute__((ext_vector_type(4))) u16   u16x4;

// ---------------- helpers ----------------
__device__ __forceinline__ u16 f2bf(float x) {
  u32 u = __builtin_bit_cast(u32, x);
  u = (u + 0x7fffu + ((u >> 16) & 1u)) >> 16;
  return (u16)u;
}
__device__ __forceinline__ float bf2f(u16 h) {
  return __builtin_bit_cast(float, (u32)h << 16);
}
__device__ __forceinline__ float fast_sig(float x) { return 1.f / (1.f + __expf(-x)); }
__device__ __forceinline__ float fast_tanh(float x) {
  float e = __expf(2.f * x);
  return 1.f - 2.f / (e + 1.f);
}

__device__ __forceinline__ f32x4 mfma_bf16(u16x8 a, u16x8 b, f32x4 c) {
  asm volatile("v_mfma_f32_16x16x32_bf16 %0, %1, %2, %0" : "+v"(c) : "v"(a), "v"(b));
  return c;
}

__device__ __forceinline__ void gload_lds16(const void* g, void* l) {
  __builtin_amdgcn_global_load_lds(
      (__attribute__((address_space(1))) u32*)g,
      (__attribute__((address_space(3))) u32*)l, 16, 0, 0);
}

// ---------------- prep kernels ----------------
__global__ __launch_bounds__(256) void k_f32_to_bf16(const float* __restrict__ s,
                                                     u16* __restrict__ d, int n) {
  int i = (blockIdx.x * 256 + threadIdx.x) * 4;
  if (i + 4 <= n) {
    f32x4 v = *(const f32x4*)(s + i);
    u16x4 o;
    o.x = f2bf(v.x); o.y = f2bf(v.y); o.z = f2bf(v.z); o.w = f2bf(v.w);
    *(u16x4*)(d + i) = o;
  } else {
    for (; i < n; ++i) d[i] = f2bf(s[i]);
  }
}

// W_gen padded to 6656 rows (rows >= 6624 zero)
__global__ __launch_bounds__(256) void k_build_wgen(const float* __restrict__ Wg,
                                                    u16* __restrict__ d) {
  int i = blockIdx.x * 256 + threadIdx.x;  // [0, 6656*512)
  int r = i >> 9;
  d[i] = f2bf(r < 6624 ? Wg[i] : 0.f);
}

__global__ __launch_bounds__(256) void k_bias_cat(const float* __restrict__ a,
                                                  const float* __restrict__ b,
                                                  float* __restrict__ d) {
  int i = blockIdx.x * 256 + threadIdx.x;  // 2048
  d[i] = a[i] + b[i];
}

// WT[k][j] = W_h2h[j][k], 512x512, bf16 (k-major for coalesced GEMV in attention)
__global__ __launch_bounds__(256) void k_transpose_w(const float* __restrict__ in,
                                                     u16* __restrict__ out) {
  __shared__ u16 t[32][33];
  const int bx = blockIdx.x * 32;
  const int by = blockIdx.y * 32;
  const int tx = threadIdx.x & 31, ty4 = (threadIdx.x >> 5) * 4;
#pragma unroll
  for (int i = 0; i < 4; ++i)
    t[ty4 + i][tx] = f2bf(in[(size_t)(by + ty4 + i) * 512 + bx + tx]);
  __syncthreads();
#pragma unroll
  for (int i = 0; i < 4; ++i)
    out[(size_t)(bx + ty4 + i) * 512 + by + tx] = t[tx][ty4 + i];
}

// ---------------- big GEMM: C[M,N] = A[M,K] * B[N,K]^T (+bias), BK=32 ----------------
// OUT_MODE: 1 = f32 + bias, 2 = bf16 (no bias)
template <int BM, int BN, int WM, int WN, int OUT_MODE>
__global__ __launch_bounds__(256) void gemm_bt(const u16* __restrict__ A, int lda,
                                               const u16* __restrict__ B, int ldb,
                                               const float* __restrict__ bias,
                                               float* __restrict__ Cf, u16* __restrict__ Cb,
                                               int ldc, int Nreal, int K) {
  static_assert((BM / WM) * (BN / WN) == 4, "4 waves");
  constexpr int FM = WM / 16, FN = WN / 16;
  constexpr int NWC = BN / WN;
  constexpr int CHA = (BM * 4) / 256, CHB = (BN * 4) / 256;
  __shared__ __align__(16) u16 sA[BM * 32];
  __shared__ __align__(16) u16 sB[BN * 32];
  const int tid = threadIdx.x;
  const int lane = tid & 63, wave = tid >> 6;
  const int wr = wave / NWC, wc = wave % NWC;
  const int l15 = lane & 15, lhi = lane >> 4;
  const int m0 = blockIdx.y * BM, n0 = blockIdx.x * BN;

  f32x4 acc[FM][FN];
#pragma unroll
  for (int i = 0; i < FM; ++i)
#pragma unroll
    for (int j = 0; j < FN; ++j) acc[i][j] = 0.f;

  for (int k0 = 0; k0 < K; k0 += 32) {
    __syncthreads();
#pragma unroll
    for (int j = 0; j < CHA; ++j) {
      int idx = j * 256 + tid;
      int row = idx >> 2, cc = idx & 3;
      int c = cc ^ ((row >> 1) & 3);
      gload_lds16(A + (size_t)(m0 + row) * lda + (k0 + c * 8), sA + idx * 8);
    }
#pragma unroll
    for (int j = 0; j < CHB; ++j) {
      int idx = j * 256 + tid;
      int row = idx >> 2, cc = idx & 3;
      int c = cc ^ ((row >> 1) & 3);
      gload_lds16(B + (size_t)(n0 + row) * ldb + (k0 + c * 8), sB + idx * 8);
    }
    __syncthreads();

    u16x8 av[FM], bv[FN];
#pragma unroll
    for (int mi = 0; mi < FM; ++mi) {
      int row = wr * WM + mi * 16 + l15;
      int ch = row * 4 + (lhi ^ ((row >> 1) & 3));
      av[mi] = *(const u16x8*)(sA + ch * 8);
    }
#pragma unroll
    for (int ni = 0; ni < FN; ++ni) {
      int row = wc * WN + ni * 16 + l15;
      int ch = row * 4 + (lhi ^ ((row >> 1) & 3));
      bv[ni] = *(const u16x8*)(sB + ch * 8);
    }
#pragma unroll
    for (int mi = 0; mi < FM; ++mi)
#pragma unroll
      for (int ni = 0; ni < FN; ++ni) acc[mi][ni] = mfma_bf16(av[mi], bv[ni], acc[mi][ni]);
  }

  asm volatile("s_nop 7\ns_nop 7\ns_nop 7");  // MFMA->VALU hazard guard

#pragma unroll
  for (int mi = 0; mi < FM; ++mi) {
#pragma unroll
    for (int ni = 0; ni < FN; ++ni) {
      int col = n0 + wc * WN + ni * 16 + l15;
      if (col < Nreal) {
        float bvv = (OUT_MODE == 1) ? bias[col] : 0.f;
#pragma unroll
        for (int r = 0; r < 4; ++r) {
          int row = m0 + wr * WM + mi * 16 + lhi * 4 + r;
          float v = acc[mi][ni][r] + bvv;
          if (OUT_MODE == 2)
            Cb[(size_t)row * ldc + col] = f2bf(v);
          else
            Cf[(size_t)row * ldc + col] = v;
        }
      }
    }
  }
}

// ---------------- K1: block-specialized {attention | gates_h GEMM} ----------------
// blocks 0..255  : per-b attention (hp GEMV + scores + softmax + ctx + ce)
// blocks 256..319: ghbuf[256,2048] = h @ W_hh^T  (BM=64, BN=128, K=512, BK=64)
__global__ __launch_bounds__(256) void k1_attn_gh(const u16* __restrict__ Hproj,
                                                  const u16* __restrict__ WT,
                                                  const float* __restrict__ b_h2h,
                                                  const float* __restrict__ wsc,
                                                  const u16* __restrict__ bh,
                                                  const u16* __restrict__ embb,
                                                  const int* __restrict__ text, int step,
                                                  u16* __restrict__ Acat,
                                                  const u16* __restrict__ Whhb,
                                                  float* __restrict__ ghbuf) {
  __shared__ __align__(16) char smem[24576];
  const int tid = threadIdx.x;

  if (blockIdx.x >= 256) {
    // ---- gates_h GEMM ----
    u16* sA = (u16*)smem;           // 64 x 64
    u16* sB = (u16*)(smem + 8192);  // 128 x 64
    const int bid = (int)blockIdx.x - 256;
    const int b0 = (bid >> 4) * 64, n0 = (bid & 15) * 128;
    const int lane = tid & 63, wave = tid >> 6;
    const int wr = wave >> 1, wc = wave & 1;
    const int l15 = lane & 15, lhi = lane >> 4;
    f32x4 acc[2][4];
#pragma unroll
    for (int i = 0; i < 2; ++i)
#pragma unroll
      for (int j = 0; j < 4; ++j) acc[i][j] = 0.f;

    for (int k0 = 0; k0 < 512; k0 += 64) {
      __syncthreads();
#pragma unroll
      for (int j = 0; j < 2; ++j) {  // A: 64 rows x 8 chunks
        int idx = j * 256 + tid, row = idx >> 3, cc = idx & 7, c = cc ^ (row & 7);
        gload_lds16(Acat + (size_t)(b0 + row) * 1280 + 768 + k0 + c * 8, sA + idx * 8);
      }
#pragma unroll
      for (int j = 0; j < 4; ++j) {  // B: 128 rows x 8 chunks
        int idx = j * 256 + tid, row = idx >> 3, cc = idx & 7, c = cc ^ (row & 7);
        gload_lds16(Whhb + (size_t)(n0 + row) * 512 + k0 + c * 8, sB + idx * 8);
      }
      __syncthreads();

#pragma unroll
      for (int ks = 0; ks < 2; ++ks) {
        u16x8 av[2], bv[4];
#pragma unroll
        for (int mi = 0; mi < 2; ++mi) {
          int row = wr * 32 + mi * 16 + l15;
          int ch = row * 8 + ((ks * 4 + lhi) ^ (row & 7));
          av[mi] = *(const u16x8*)(sA + ch * 8);
        }
#pragma unroll
        for (int ni = 0; ni < 4; ++ni) {
          int row = wc * 64 + ni * 16 + l15;
          int ch = row * 8 + ((ks * 4 + lhi) ^ (row & 7));
          bv[ni] = *(const u16x8*)(sB + ch * 8);
        }
#pragma unroll
        for (int mi = 0; mi < 2; ++mi)
#pragma unroll
          for (int ni = 0; ni < 4; ++ni) acc[mi][ni] = mfma_bf16(av[mi], bv[ni], acc[mi][ni]);
      }
    }
    asm volatile("s_nop 7\ns_nop 7\ns_nop 7");
#pragma unroll
    for (int mi = 0; mi < 2; ++mi)
#pragma unroll
      for (int ni = 0; ni < 4; ++ni) {
        int col = n0 + wc * 64 + ni * 16 + l15;
        int row = b0 + wr * 32 + mi * 16 + lhi * 4;
#pragma unroll
        for (int r = 0; r < 4; ++r) ghbuf[(size_t)(row + r) * 2048 + col] = acc[mi][ni][r];
      }
    return;
  }

  // ---- attention path ----
  float* hsm = (float*)smem;                          // 512
  float (*part)[512] = (float(*)[512])(smem + 2048);  // 4 x 512
  float* hpsp = (float*)(smem + 10240);               // 528 (padded j + (j>>5))
  float* wssp = (float*)(smem + 12352);               // 528
  float* es   = (float*)(smem + 14464);               // 64
  const int b = blockIdx.x;

  {  // load h (prev step) and w_score
    u32 w2 = *(const u32*)(Acat + b * 1280 + 768 + tid * 2);
    hsm[tid * 2] = bf2f((u16)(w2 & 0xffffu));
    hsm[tid * 2 + 1] = bf2f((u16)(w2 >> 16));
    int j0 = tid * 2;
    int pi = j0 + (j0 >> 5);
    wssp[pi] = wsc[j0];
    wssp[pi + 1] = wsc[j0 + 1];
  }
  __syncthreads();

  {  // hp partials: kg in [0,4), cols cg*8..cg*8+7
    const int kg = tid >> 6, cg = tid & 63;
    float acc[8] = {0.f, 0.f, 0.f, 0.f, 0.f, 0.f, 0.f, 0.f};
    const u16* wrow = WT + (size_t)(kg * 128) * 512 + cg * 8;
#pragma unroll 4
    for (int kk = 0; kk < 128; ++kk) {
      float hk = hsm[kg * 128 + kk];
      u16x8 wv = *(const u16x8*)(wrow + (size_t)kk * 512);
#pragma unroll
      for (int j = 0; j < 8; ++j) acc[j] = fmaf(hk, bf2f(wv[j]), acc[j]);
    }
#pragma unroll
    for (int j = 0; j < 8; ++j) part[kg][cg * 8 + j] = acc[j];
  }
  __syncthreads();
  {  // reduce + bias -> padded hp
    int j0 = tid * 2;
#pragma unroll
    for (int q = 0; q < 2; ++q) {
      int j = j0 + q;
      float v = part[0][j] + part[1][j] + part[2][j] + part[3][j] + b_h2h[j];
      hpsp[j + (j >> 5)] = v;
    }
  }
  __syncthreads();

  const int ch16 = tid & 15;
  const int hbase = ch16 * 33;
  const int hc = ch16 * 32;
  float hpr[32], wsr[32];
#pragma unroll
  for (int j = 0; j < 32; ++j) {
    hpr[j] = hpsp[hbase + j];
    wsr[j] = wssp[hbase + j];
  }
#pragma unroll
  for (int tg = 0; tg < 4; ++tg) {
    int t = tg * 16 + (tid >> 4);
    const u16* hr = Hproj + (size_t)(b * 64 + t) * 512 + hc;
    float s = 0.f;
#pragma unroll
    for (int jo = 0; jo < 32; jo += 8) {
      u16x8 hv = *(const u16x8*)(hr + jo);
#pragma unroll
      for (int j = 0; j < 8; ++j) {
        float x = bf2f(hv[j]) + hpr[jo + j];
        s += fast_tanh(x) * wsr[jo + j];
      }
    }
#pragma unroll
    for (int off = 8; off; off >>= 1) s += __shfl_xor(s, off, 16);
    if (ch16 == 0) es[t] = s;
  }
  __syncthreads();
  if (tid < 64) {  // softmax over t
    float v = es[tid];
    float m = v;
#pragma unroll
    for (int o = 32; o; o >>= 1) m = fmaxf(m, __shfl_xor(m, o, 64));
    float p = __expf(v - m);
    float su = p;
#pragma unroll
    for (int o = 32; o; o >>= 1) su += __shfl_xor(su, o, 64);
    es[tid] = p / su;
  }
  __syncthreads();
  // context + ce gather
  const u16* base = bh + (size_t)b * 32768 + tid * 2;
  float c0 = 0.f, c1 = 0.f;
#pragma unroll 8
  for (int t = 0; t < 64; ++t) {
    u32 w = *(const u32*)(base + t * 512);
    float a = es[t];
    c0 = fmaf(a, bf2f((u16)(w & 0xffffu)), c0);
    c1 = fmaf(a, bf2f((u16)(w >> 16)), c1);
  }
  u32 pk = (u32)f2bf(c0) | ((u32)f2bf(c1) << 16);
  *(u32*)(Acat + b * 1280 + tid * 2) = pk;
  int ci = text[b * 26 + step];
  Acat[b * 1280 + 512 + tid] = embb[(size_t)ci * 256 + tid];
}

// ---------------- K2: gates_x GEMM (K=768) + ghbuf + bias + LSTM ----------------
// grid (16, 8): jt = 32-wide j-tile (x4 gate segs gathered -> BN=128), b0 = 32-wide
// batch tile (BM=32). BK=64, 12 K-iters. LDS reused for the gate exchange.
__global__ __launch_bounds__(256) void k2_gates_lstm(const u16* __restrict__ Wihb,
                                                     const float* __restrict__ biascat,
                                                     const float* __restrict__ ghbuf,
                                                     float* __restrict__ cst,
                                                     u16* __restrict__ Acat,
                                                     u16* __restrict__ hsb, int step) {
  __shared__ __align__(16) char smem[20480];  // sA 4KB + sB 16KB; reused: gsm 32x132 f32
  u16* sA = (u16*)smem;           // 32 x 64
  u16* sB = (u16*)(smem + 4096);  // 128 x 64
  const int tid = threadIdx.x;
  const int lane = tid & 63, wave = tid >> 6;
  const int wr = wave >> 1, wc = wave & 1;  // WM=16, WN=64
  const int l15 = lane & 15, lhi = lane >> 4;
  const int jt = blockIdx.x;       // 0..15, 32 j's each
  const int b0 = blockIdx.y * 32;  // 0..7

  f32x4 acc[4];
#pragma unroll
  for (int j = 0; j < 4; ++j) acc[j] = 0.f;

  for (int k0 = 0; k0 < 768; k0 += 64) {
    __syncthreads();
    {  // A: 32 rows x 8 chunks = 256
      int row = tid >> 3, cc = tid & 7, c = cc ^ (row & 7);
      gload_lds16(Acat + (size_t)(b0 + row) * 1280 + k0 + c * 8, sA + tid * 8);
    }
#pragma unroll
    for (int j = 0; j < 4; ++j) {  // B: 128 rows (4 segs x 32 j) x 8 chunks
      int idx = j * 256 + tid, row = idx >> 3, cc = idx & 7, c = cc ^ (row & 7);
      int grow = (row >> 5) * 512 + jt * 32 + (row & 31);
      gload_lds16(Wihb + (size_t)grow * 768 + k0 + c * 8, sB + idx * 8);
    }
    __syncthreads();

#pragma unroll
    for (int ks = 0; ks < 2; ++ks) {
      u16x8 av, bv[4];
      {
        int row = wr * 16 + l15;
        int ch = row * 8 + ((ks * 4 + lhi) ^ (row & 7));
        av = *(const u16x8*)(sA + ch * 8);
      }
#pragma unroll
      for (int ni = 0; ni < 4; ++ni) {
        int row = wc * 64 + ni * 16 + l15;
        int ch = row * 8 + ((ks * 4 + lhi) ^ (row & 7));
        bv[ni] = *(const u16x8*)(sB + ch * 8);
      }
#pragma unroll
      for (int ni = 0; ni < 4; ++ni) acc[ni] = mfma_bf16(av, bv[ni], acc[ni]);
    }
  }

  asm volatile("s_nop 7\ns_nop 7\ns_nop 7");  // MFMA->VALU hazard guard
  __syncthreads();                            // staging reads done -> reuse LDS
  float (*gsm)[132] = (float(*)[132])smem;    // 32 x 132 = 16.9 KB
#pragma unroll
  for (int ni = 0; ni < 4; ++ni) {
    int col = wc * 64 + ni * 16 + l15;
    int row = wr * 16 + lhi * 4;
#pragma unroll
    for (int r = 0; r < 4; ++r) gsm[row + r][col] = acc[ni][r];
  }
  __syncthreads();

  {  // LSTM: thread owns bl = tid>>3 (32 b's), 4 j's at jl0 = (tid&7)*4
    const int bl = tid >> 3, jl0 = (tid & 7) * 4;
    const int b = b0 + bl;
    const int jg0 = jt * 32 + jl0;
    const float* gh = ghbuf + (size_t)b * 2048;
    float cn[4];
    u16 hb[4];
#pragma unroll
    for (int q = 0; q < 4; ++q) {
      int jl = jl0 + q, j = jg0 + q;
      float gi = gsm[bl][jl]      + gh[j]        + biascat[j];
      float gf = gsm[bl][32 + jl] + gh[512 + j]  + biascat[512 + j];
      float gg = gsm[bl][64 + jl] + gh[1024 + j] + biascat[1024 + j];
      float go = gsm[bl][96 + jl] + gh[1536 + j] + biascat[1536 + j];
      float c = fast_sig(gf) * cst[(size_t)b * 512 + j] + fast_sig(gi) * fast_tanh(gg);
      cn[q] = c;
      hb[q] = f2bf(fast_sig(go) * fast_tanh(c));
    }
    *(f32x4*)(cst + (size_t)b * 512 + jg0) = *(f32x4*)cn;
    *(u16x4*)(Acat + (size_t)b * 1280 + 768 + jg0) = *(u16x4*)hb;
    *(u16x4*)(hsb + (size_t)(b * 26 + step) * 512 + jg0) = *(u16x4*)hb;
  }
}

// ---------------- launch ----------------
extern "C" void kernel_launch(void* const* d_in, const int* in_sizes, int n_in,
                              void* d_out, int out_size, void* d_ws, size_t ws_size,
                              hipStream_t stream) {
  const float* batch_H = (const float*)d_in[0];
  const int*   text    = (const int*)d_in[1];
  const float* W_i2h   = (const float*)d_in[2];
  const float* W_h2h   = (const float*)d_in[3];
  const float* b_h2h   = (const float*)d_in[4];
  const float* w_score = (const float*)d_in[5];
  const float* W_ih    = (const float*)d_in[6];
  const float* W_hh    = (const float*)d_in[7];
  const float* b_ih    = (const float*)d_in[8];
  const float* b_hh    = (const float*)d_in[9];
  const float* emb     = (const float*)d_in[10];
  const float* W_gen   = (const float*)d_in[11];
  const float* b_gen   = (const float*)d_in[12];
  float* out = (float*)d_out;

  // Big bf16 scratch at the front of d_out (fully overwritten by the final GEMM,
  // which reads only hsb/Wgenb).
  u16* bHb   = (u16*)d_out;          // 16 MB
  u16* Hproj = bHb + 8388608;        // 16 MB

  char* w = (char*)d_ws;
  auto alloc = [&](size_t bytes) {
    char* p = w;
    w += (bytes + 255) & ~(size_t)255;
    return p;
  };
  u16*   Wi2hb   = (u16*)alloc(512ull * 512 * 2);
  u16*   WTb     = (u16*)alloc(512ull * 512 * 2);   // W_h2h^T, k-major
  u16*   Wihb    = (u16*)alloc(2048ull * 768 * 2);
  u16*   Whhb    = (u16*)alloc(2048ull * 512 * 2);
  u16*   Wgenb   = (u16*)alloc(6656ull * 512 * 2);
  u16*   embb    = (u16*)alloc(6624ull * 256 * 2);
  float* biascat = (float*)alloc(2048ull * 4);
  u16*   Acat    = (u16*)alloc(256ull * 1280 * 2);  // [ctx(512) | ce(256) | h(512)]
  float* cst     = (float*)alloc(256ull * 512 * 4);
  float* ghbuf   = (float*)alloc(256ull * 2048 * 4);
  u16*   hsb     = (u16*)alloc(6656ull * 512 * 2);

  hipMemsetAsync(Acat, 0, 256ull * 1280 * 2, stream);  // h0 = 0
  hipMemsetAsync(cst, 0, 256ull * 512 * 4, stream);    // c0 = 0

  k_f32_to_bf16<<<8192, 256, 0, stream>>>(batch_H, bHb, 8388608);
  k_f32_to_bf16<<<256, 256, 0, stream>>>(W_i2h, Wi2hb, 262144);
  k_transpose_w<<<dim3(16, 16), 256, 0, stream>>>(W_h2h, WTb);
  k_f32_to_bf16<<<1656, 256, 0, stream>>>(emb, embb, 1695744);
  k_f32_to_bf16<<<1536, 256, 0, stream>>>(W_ih, Wihb, 1572864);
  k_f32_to_bf16<<<1024, 256, 0, stream>>>(W_hh, Whhb, 1048576);
  k_build_wgen<<<13312, 256, 0, stream>>>(W_gen, Wgenb);
  k_bias_cat<<<8, 256, 0, stream>>>(b_ih, b_hh, biascat);

  // Hproj = batch_H @ W_i2h^T -> bf16
  gemm_bt<128, 128, 64, 64, 2><<<dim3(4, 128), 256, 0, stream>>>(
      bHb, 512, Wi2hb, 512, nullptr, nullptr, Hproj, 512, 512, 512);

  for (int s = 0; s < 26; ++s) {
    k1_attn_gh<<<320, 256, 0, stream>>>(Hproj, WTb, b_h2h, w_score, bHb, embb, text, s,
                                        Acat, Whhb, ghbuf);
    k2_gates_lstm<<<dim3(16, 8), 256, 0, stream>>>(Wihb, biascat, ghbuf, cst, Acat, hsb, s);
  }

  // probs = hs @ W_gen^T + b_gen -> f32 out (M=6656, N=6624, K=512)
  gemm_bt<128, 128, 64, 64, 1><<<dim3(52, 52), 256, 0, stream>>>(
      hsb, 512, Wgenb, 512, b_gen, out, nullptr, 6624, 6624, 512);

  (void)in_sizes; (void)n_in; (void)out_size; (void)ws_size;
}